// Round 7
// baseline (7204.005 us; speedup 1.0000x reference)
//
#include <hip/hip_runtime.h>
#include <math.h>

#define N_NODES 100000
#define N_EDGES 3200000
#define NCLASS  64
#define TOPK    16
#define NHID    128
#define DEG     6

#define BROWS   128                       // rows per bucket
#define NBUCK   ((N_NODES + BROWS - 1) / BROWS)   // 782
#define BUCKCAP 4608                      // mean 4092 + ~8 sigma

// ---------- bf16 helpers ----------
__device__ __forceinline__ float bf2f(unsigned short u) {
    return __uint_as_float(((unsigned)u) << 16);
}
__device__ __forceinline__ unsigned short f2bf(float f) {
    unsigned u = __float_as_uint(f);
    u = (u + 0x7FFFu + ((u >> 16) & 1u)) >> 16;   // round-to-nearest-even
    return (unsigned short)u;
}

// ---------- wave helpers (wave64) ----------
__device__ __forceinline__ float wave_max(float v) {
    #pragma unroll
    for (int off = 1; off < 64; off <<= 1) v = fmaxf(v, __shfl_xor(v, off));
    return v;
}
__device__ __forceinline__ float wave_sum(float v) {
    #pragma unroll
    for (int off = 1; off < 64; off <<= 1) v += __shfl_xor(v, off);
    return v;
}

// ---------- bucket scatter: direct (r5 structure — fastest measured) ----------
// (col<<8 | row_local) packed with val into 8B; bucket-major staging.
__global__ void phase1_bucket(const int* __restrict__ erow, const int* __restrict__ ecol,
                              const float* __restrict__ eval, int* __restrict__ fill,
                              int2* __restrict__ staging) {
    int i = blockIdx.x * 256 + threadIdx.x;
    if (i < N_EDGES) {
        int   r = __builtin_nontemporal_load(&erow[i]);
        int   c = __builtin_nontemporal_load(&ecol[i]);
        float w = __builtin_nontemporal_load(&eval[i]);
        int b = r >> 7;
        int pos = atomicAdd(&fill[b * 16], 1);
        if (pos < BUCKCAP) {
            int2 e;
            e.x = (c << 8) | (r & 127);
            e.y = __float_as_int(w);
            staging[(size_t)b * BUCKCAP + pos] = e;
        }
    }
}

// ---------- gating: bitonic sort64 -> top16 softmax -> MLP -> softmax6 ----------
#define GNODES 32   // nodes per block (4 waves x 8 iterations)
__global__ __launch_bounds__(256) void gating_kernel(
        const float* __restrict__ x,  const float* __restrict__ W1,
        const float* __restrict__ b1, const float* __restrict__ W2,
        const float* __restrict__ b2, float* __restrict__ weight,
        float* __restrict__ out_acc, unsigned short* __restrict__ xbf) {
    __shared__ float sW1t[TOPK * NHID];   // transposed: [k][j]
    __shared__ float sb1[NHID];
    __shared__ float sW2[DEG * NHID];
    __shared__ float sb2[DEG];
    int tid = threadIdx.x;
    for (int idx = tid; idx < NHID * TOPK; idx += 256) {
        int k = idx / NHID, j = idx - k * NHID;
        sW1t[idx] = W1[j * TOPK + k];
    }
    for (int i = tid; i < NHID; i += 256) sb1[i] = b1[i];
    for (int i = tid; i < DEG * NHID; i += 256) sW2[i] = W2[i];
    if (tid < DEG) sb2[tid] = b2[tid];
    __syncthreads();

    int wave = tid >> 6;
    int lane = tid & 63;

    for (int it = 0; it < GNODES / 4; it++) {
        int node = blockIdx.x * GNODES + it * 4 + wave;
        if (node >= N_NODES) continue;

        float xv = x[node * NCLASS + lane];
        xbf[node * NCLASS + lane] = f2bf(xv);

        // full ascending bitonic sort of x across the wave (21 steps)
        float v = xv;
        #pragma unroll
        for (int k = 2; k <= 64; k <<= 1) {
            #pragma unroll
            for (int j = k >> 1; j > 0; j >>= 1) {
                float o = __shfl_xor(v, j);
                bool keep_small = (((lane & j) == 0) == ((lane & k) == 0));
                v = keep_small ? fminf(v, o) : fmaxf(v, o);
            }
        }
        float m = __shfl(v, 63);                 // global max
        float e = __expf(v - m);
        float s = wave_sum(e);                   // softmax denominator
        float inv_s = 1.0f / s;

        float h0 = sb1[lane], h1 = sb1[lane + 64];
        #pragma unroll
        for (int k = 0; k < TOPK; k++) {
            float sv = __shfl(v, 63 - k);        // k-th largest logit
            float tk = __expf(sv - m) * inv_s;   // k-th largest prob
            h0 += tk * sW1t[k * NHID + lane];
            h1 += tk * sW1t[k * NHID + lane + 64];
        }
        h0 = (h0 > 0.f) ? h0 : 0.1f * h0;
        h1 = (h1 > 0.f) ? h1 : 0.1f * h1;

        float w[DEG];
        float wm = -1e30f;
        #pragma unroll
        for (int d = 0; d < DEG; d++) {
            float part = h0 * sW2[d * NHID + lane] + h1 * sW2[d * NHID + lane + 64];
            w[d] = wave_sum(part) + sb2[d];
            wm = fmaxf(wm, w[d]);
        }
        float wsum = 0.f;
        #pragma unroll
        for (int d = 0; d < DEG; d++) { w[d] = __expf(w[d] - wm); wsum += w[d]; }
        float inv = 1.0f / wsum;

        if (lane < DEG) weight[node * DEG + lane] = w[lane] * inv;
        out_acc[node * NCLASS + lane] = w[0] * inv * xv;
    }
}

// ---------- SPMM hop: block = bucket, LDS fp32 accumulator tile ----------
// Consumes bucket-major staging directly (no CSR compaction pass).
__global__ __launch_bounds__(256) void spmm_kernel(
        const unsigned short* __restrict__ src, unsigned short* __restrict__ dst,
        const int* __restrict__ fill, const int2* __restrict__ staging,
        const float* __restrict__ weight,
        float* __restrict__ out_acc, float* __restrict__ final_out,
        int hop, int is_last) {
    __shared__ float sacc[BROWS * NCLASS];   // 32 KB
    int b = blockIdx.x;
    int tid = threadIdx.x, wv = tid >> 6, lane = tid & 63;

    #pragma unroll
    for (int i = tid; i < BROWS * NCLASS; i += 256) sacc[i] = 0.f;
    __syncthreads();

    int n = min(fill[b * 16], BUCKCAP);
    const long long* edq = (const long long*)(staging + (size_t)b * BUCKCAP);

    // split bucket's edges across 4 waves; 8 independent gathers in flight
    int per = (n + 3) >> 2;
    int s0 = wv * per;
    int e0 = min(s0 + per, n);
    int i = s0;
    for (; i + 8 <= e0; i += 8) {
        long long q[8];
        #pragma unroll
        for (int k = 0; k < 8; k++) q[k] = __builtin_nontemporal_load(&edq[i + k]);
        int   pk[8]; float vk[8], fk[8];
        #pragma unroll
        for (int k = 0; k < 8; k++) {
            pk[k] = __builtin_amdgcn_readfirstlane((int)(unsigned)q[k]);
            vk[k] = __int_as_float(__builtin_amdgcn_readfirstlane((int)(q[k] >> 32)));
            fk[k] = bf2f(src[(pk[k] >> 8) * NCLASS + lane]);
        }
        #pragma unroll
        for (int k = 0; k < 8; k++)
            atomicAdd(&sacc[(pk[k] & 127) * NCLASS + lane], vk[k] * fk[k]);
    }
    for (; i < e0; i++) {
        long long q0 = __builtin_nontemporal_load(&edq[i]);
        int   p0 = __builtin_amdgcn_readfirstlane((int)(unsigned)q0);
        float v0 = __int_as_float(__builtin_amdgcn_readfirstlane((int)(q0 >> 32)));
        float f0 = bf2f(src[(p0 >> 8) * NCLASS + lane]);
        atomicAdd(&sacc[(p0 & 127) * NCLASS + lane], v0 * f0);
    }
    __syncthreads();

    // coalesced write-out: wave wv owns rows wv, wv+4, ...
    int base = b * BROWS;
    for (int r = wv; r < BROWS; r += 4) {
        int node = base + r;
        if (node >= N_NODES) break;
        float a = sacc[r * NCLASS + lane];
        float w = weight[node * DEG + hop];
        if (!is_last) {
            dst[node * NCLASS + lane] = f2bf(a);
            out_acc[node * NCLASS + lane] += w * a;
        } else {
            float v = out_acc[node * NCLASS + lane] + w * a;
            float m = wave_max(v);
            float e2 = __expf(v - m);
            float sden = wave_sum(e2);
            final_out[node * NCLASS + lane] = v - m - __logf(sden);
        }
    }
}

extern "C" void kernel_launch(void* const* d_in, const int* in_sizes, int n_in,
                              void* d_out, int out_size, void* d_ws, size_t ws_size,
                              hipStream_t stream) {
    const float* x    = (const float*)d_in[0];
    const int*   erow = (const int*)  d_in[1];
    const int*   ecol = (const int*)  d_in[2];
    const float* eval = (const float*)d_in[3];
    const float* W1   = (const float*)d_in[4];
    const float* b1   = (const float*)d_in[5];
    const float* W2   = (const float*)d_in[6];
    const float* b2   = (const float*)d_in[7];
    float* out = (float*)d_out;   // also the hop-accumulation buffer

    char* ws = (char*)d_ws;
    size_t off = 0;
    auto alloc = [&](size_t bytes) -> void* {
        void* p = ws + off;
        off = (off + bytes + 255) & ~(size_t)255;
        return p;
    };
    int2* staging = (int2*)alloc((size_t)NBUCK * BUCKCAP * 8);        // 28.8 MB, lives all hops
    unsigned short* xbf  = (unsigned short*)alloc((size_t)N_NODES * NCLASS * 2);
    unsigned short* cur0 = (unsigned short*)alloc((size_t)N_NODES * NCLASS * 2);
    unsigned short* cur1 = (unsigned short*)alloc((size_t)N_NODES * NCLASS * 2);
    int*   fill   = (int*)  alloc((size_t)NBUCK * 16 * 4);            // 64B-padded counters
    float* weight = (float*)alloc((size_t)N_NODES * DEG * 4);

    const int EB = (N_EDGES + 255) / 256;            // 12500
    const int GB = (N_NODES + GNODES - 1) / GNODES;  // 3125

    // bucket scatter (only CSR-ish phase left)
    hipMemsetAsync(fill, 0, (size_t)NBUCK * 16 * 4, stream);
    phase1_bucket<<<EB, 256, 0, stream>>>(erow, ecol, eval, fill, staging);

    // gating: weights + out = w0 * x, and bf16 copy of x
    gating_kernel<<<GB, 256, 0, stream>>>(x, W1, b1, W2, b2, weight, out, xbf);

    // 5 hops, out accumulated in d_out; last hop fuses log_softmax
    spmm_kernel<<<NBUCK, 256, 0, stream>>>(xbf,  cur0, fill, staging, weight, out, out, 1, 0);
    spmm_kernel<<<NBUCK, 256, 0, stream>>>(cur0, cur1, fill, staging, weight, out, out, 2, 0);
    spmm_kernel<<<NBUCK, 256, 0, stream>>>(cur1, cur0, fill, staging, weight, out, out, 3, 0);
    spmm_kernel<<<NBUCK, 256, 0, stream>>>(cur0, cur1, fill, staging, weight, out, out, 4, 0);
    spmm_kernel<<<NBUCK, 256, 0, stream>>>(cur1, cur0, fill, staging, weight, out, out, 5, 1);
}

// Round 8
// 722.073 us; speedup vs baseline: 9.9768x; 9.9768x over previous
//
#include <hip/hip_runtime.h>
#include <math.h>

#define N_NODES 100000
#define N_EDGES 3200000
#define NCLASS  64
#define TOPK    16
#define NHID    128
#define DEG     6

#define NBUCK   391          // ceil(100000/256) buckets of 256 rows
#define BUCKCAP 9216         // mean 8184 + ~11 sigma

// ---------- bf16 helpers ----------
__device__ __forceinline__ float bf2f(unsigned short u) {
    return __uint_as_float(((unsigned)u) << 16);
}
__device__ __forceinline__ unsigned short f2bf(float f) {
    unsigned u = __float_as_uint(f);
    u = (u + 0x7FFFu + ((u >> 16) & 1u)) >> 16;   // round-to-nearest-even
    return (unsigned short)u;
}

// ---------- wave helpers (wave64) ----------
__device__ __forceinline__ float wave_max(float v) {
    #pragma unroll
    for (int off = 1; off < 64; off <<= 1) v = fmaxf(v, __shfl_xor(v, off));
    return v;
}
__device__ __forceinline__ float wave_sum(float v) {
    #pragma unroll
    for (int off = 1; off < 64; off <<= 1) v += __shfl_xor(v, off);
    return v;
}

// ---------- CSR phase 1: direct bucket scatter (fastest measured form) ----------
__global__ void phase1_bucket(const int* __restrict__ erow, const int* __restrict__ ecol,
                              const float* __restrict__ eval, int* __restrict__ fill,
                              int2* __restrict__ staging) {
    int i = blockIdx.x * 256 + threadIdx.x;
    if (i < N_EDGES) {
        int   r = __builtin_nontemporal_load(&erow[i]);
        int   c = __builtin_nontemporal_load(&ecol[i]);
        float w = __builtin_nontemporal_load(&eval[i]);
        int b = r >> 8;
        int pos = atomicAdd(&fill[b * 16], 1);
        if (pos < BUCKCAP) {
            int2 e;
            e.x = (c << 8) | (r & 255);   // col:17b << 8 | row_local:8b
            e.y = __float_as_int(w);
            staging[(size_t)b * BUCKCAP + pos] = e;
        }
    }
}

// ---------- CSR: prefix over bucket totals ----------
__global__ void bucket_scan(const int* __restrict__ fill, int* __restrict__ bucket_base,
                            int* __restrict__ row_ptr) {
    __shared__ int sdat[512];
    int tid = threadIdx.x;
    int c = 0;
    if (tid < NBUCK) c = min(fill[tid * 16], BUCKCAP);
    sdat[tid] = c;
    __syncthreads();
    for (int off = 1; off < 512; off <<= 1) {
        int t = (tid >= off) ? sdat[tid - off] : 0;
        __syncthreads();
        sdat[tid] += t;
        __syncthreads();
    }
    if (tid < NBUCK) bucket_base[tid] = sdat[tid] - c;   // exclusive
    if (tid == 0) row_ptr[N_NODES] = sdat[511];          // == N_EDGES
}

// ---------- CSR phase 2: per-bucket compaction + row_ptr ----------
__global__ __launch_bounds__(256) void phase2_build(
        const int2* __restrict__ staging, const int* __restrict__ fill,
        const int* __restrict__ bucket_base, int* __restrict__ row_ptr,
        int2* __restrict__ edges_s) {
    __shared__ int lhist[256];
    __shared__ int lscan[256];
    __shared__ int lfill[256];
    int b = blockIdx.x, tid = threadIdx.x;
    int c = min(fill[b * 16], BUCKCAP);
    const int2* seg = staging + (size_t)b * BUCKCAP;
    lhist[tid] = 0;
    __syncthreads();
    for (int j = tid; j < c; j += 256) atomicAdd(&lhist[seg[j].x & 255], 1);
    __syncthreads();
    int v = lhist[tid];
    lscan[tid] = v;
    __syncthreads();
    for (int off = 1; off < 256; off <<= 1) {
        int t = (tid >= off) ? lscan[tid - off] : 0;
        __syncthreads();
        lscan[tid] += t;
        __syncthreads();
    }
    int excl = bucket_base[b] + (lscan[tid] - v);
    int grow = b * 256 + tid;
    if (grow < N_NODES) row_ptr[grow] = excl;
    lfill[tid] = excl;
    __syncthreads();
    for (int j = tid; j < c; j += 256) {
        int2 e = seg[j];
        int rl = e.x & 255;
        int pos = atomicAdd(&lfill[rl], 1);
        edges_s[pos] = make_int2((int)(((unsigned)e.x) >> 8), e.y);
    }
}

// ---------- gating: bitonic sort64 -> top16 softmax -> MLP -> softmax6 ----------
#define GNODES 32   // nodes per block (4 waves x 8 iterations)
__global__ __launch_bounds__(256) void gating_kernel(
        const float* __restrict__ x,  const float* __restrict__ W1,
        const float* __restrict__ b1, const float* __restrict__ W2,
        const float* __restrict__ b2, float* __restrict__ weight,
        float* __restrict__ out_acc, unsigned short* __restrict__ xbf) {
    __shared__ float sW1t[TOPK * NHID];   // transposed: [k][j]
    __shared__ float sb1[NHID];
    __shared__ float sW2[DEG * NHID];
    __shared__ float sb2[DEG];
    int tid = threadIdx.x;
    for (int idx = tid; idx < NHID * TOPK; idx += 256) {
        int k = idx / NHID, j = idx - k * NHID;
        sW1t[idx] = W1[j * TOPK + k];
    }
    for (int i = tid; i < NHID; i += 256) sb1[i] = b1[i];
    for (int i = tid; i < DEG * NHID; i += 256) sW2[i] = W2[i];
    if (tid < DEG) sb2[tid] = b2[tid];
    __syncthreads();

    int wave = tid >> 6;
    int lane = tid & 63;

    for (int it = 0; it < GNODES / 4; it++) {
        int node = blockIdx.x * GNODES + it * 4 + wave;
        if (node >= N_NODES) continue;

        float xv = x[node * NCLASS + lane];
        xbf[node * NCLASS + lane] = f2bf(xv);

        // full ascending bitonic sort of x across the wave (21 steps)
        float v = xv;
        #pragma unroll
        for (int k = 2; k <= 64; k <<= 1) {
            #pragma unroll
            for (int j = k >> 1; j > 0; j >>= 1) {
                float o = __shfl_xor(v, j);
                bool keep_small = (((lane & j) == 0) == ((lane & k) == 0));
                v = keep_small ? fminf(v, o) : fmaxf(v, o);
            }
        }
        float m = __shfl(v, 63);                 // global max
        float e = __expf(v - m);
        float s = wave_sum(e);                   // softmax denominator
        float inv_s = 1.0f / s;

        float h0 = sb1[lane], h1 = sb1[lane + 64];
        #pragma unroll
        for (int k = 0; k < TOPK; k++) {
            float sv = __shfl(v, 63 - k);        // k-th largest logit
            float tk = __expf(sv - m) * inv_s;   // k-th largest prob
            h0 += tk * sW1t[k * NHID + lane];
            h1 += tk * sW1t[k * NHID + lane + 64];
        }
        h0 = (h0 > 0.f) ? h0 : 0.1f * h0;
        h1 = (h1 > 0.f) ? h1 : 0.1f * h1;

        float w[DEG];
        float wm = -1e30f;
        #pragma unroll
        for (int d = 0; d < DEG; d++) {
            float part = h0 * sW2[d * NHID + lane] + h1 * sW2[d * NHID + lane + 64];
            w[d] = wave_sum(part) + sb2[d];
            wm = fmaxf(wm, w[d]);
        }
        float wsum = 0.f;
        #pragma unroll
        for (int d = 0; d < DEG; d++) { w[d] = __expf(w[d] - wm); wsum += w[d]; }
        float inv = 1.0f / wsum;

        if (lane < DEG) weight[node * DEG + lane] = w[lane] * inv;
        out_acc[node * NCLASS + lane] = w[0] * inv * xv;
    }
}

// ---------- SPMM gather groups (scalar SGPR edge stream) ----------
__device__ __forceinline__ void gather8(const unsigned short* __restrict__ src,
                                        const long long* __restrict__ edq,
                                        int e, int lane, float& acc) {
    long long q[8];
    #pragma unroll
    for (int k = 0; k < 8; k++) q[k] = __builtin_nontemporal_load(&edq[e + k]);
    float vk[8], fk[8];
    #pragma unroll
    for (int k = 0; k < 8; k++) {
        int col = __builtin_amdgcn_readfirstlane((int)(unsigned)q[k]);
        vk[k] = __int_as_float(__builtin_amdgcn_readfirstlane((int)(q[k] >> 32)));
        fk[k] = bf2f(src[col * NCLASS + lane]);
    }
    #pragma unroll
    for (int k = 0; k < 8; k++) acc += vk[k] * fk[k];
}

__device__ __forceinline__ void gather4(const unsigned short* __restrict__ src,
                                        const long long* __restrict__ edq,
                                        int e, int lane, float& acc) {
    long long q[4];
    #pragma unroll
    for (int k = 0; k < 4; k++) q[k] = __builtin_nontemporal_load(&edq[e + k]);
    float vk[4], fk[4];
    #pragma unroll
    for (int k = 0; k < 4; k++) {
        int col = __builtin_amdgcn_readfirstlane((int)(unsigned)q[k]);
        vk[k] = __int_as_float(__builtin_amdgcn_readfirstlane((int)(q[k] >> 32)));
        fk[k] = bf2f(src[col * NCLASS + lane]);
    }
    #pragma unroll
    for (int k = 0; k < 4; k++) acc += vk[k] * fk[k];
}

__device__ __forceinline__ float drain_row(const unsigned short* __restrict__ src,
                                           const long long* __restrict__ edq,
                                           int e, int end, int lane, float acc) {
    for (; e + 4 <= end; e += 4) gather4(src, edq, e, lane, acc);
    for (; e < end; e++) {
        long long q0 = __builtin_nontemporal_load(&edq[e]);
        int   c0 = __builtin_amdgcn_readfirstlane((int)(unsigned)q0);
        float v0 = __int_as_float(__builtin_amdgcn_readfirstlane((int)(q0 >> 32)));
        acc += v0 * bf2f(src[c0 * NCLASS + lane]);
    }
    return acc;
}

// ---------- SPMM hop: wave per ROW-PAIR, 16 gathers in flight ----------
// mode 0: write dst only.
// mode 1: write dst AND fold TWO weighted terms into out_acc:
//         out_acc += w[hop-1]*src[node] + w[hop]*acc   (src row = prev hop out)
// mode 2: last hop — v = out_acc + w[hop]*acc -> log_softmax -> final_out.
__global__ __launch_bounds__(256) void spmm_kernel(
        const unsigned short* __restrict__ src, unsigned short* __restrict__ dst,
        const int* __restrict__ row_ptr, const int2* __restrict__ edges_s,
        const float* __restrict__ weight,
        float* __restrict__ out_acc, float* __restrict__ final_out,
        int hop, int mode) {
    int wave = threadIdx.x >> 6;
    int lane = threadIdx.x & 63;
    int wid = blockIdx.x * 4 + wave;          // pair id
    int rA = wid * 2;
    if (rA >= N_NODES) return;
    int rB = rA + 1;                           // N_NODES even -> always valid

    int sA   = __builtin_amdgcn_readfirstlane(row_ptr[rA]);
    int endA = __builtin_amdgcn_readfirstlane(row_ptr[rA + 1]);
    int endB = __builtin_amdgcn_readfirstlane(row_ptr[rA + 2]);

    const long long* edq = (const long long*)edges_s;
    float accA = 0.f, accB = 0.f;
    int eA = sA, eB = endA;
    // interleaved: 16 independent gathers in flight from 2 chains
    while (eA + 8 <= endA && eB + 8 <= endB) {
        gather8(src, edq, eA, lane, accA);
        gather8(src, edq, eB, lane, accB);
        eA += 8; eB += 8;
    }
    accA = drain_row(src, edq, eA, endA, lane, accA);
    accB = drain_row(src, edq, eB, endB, lane, accB);

    float wA = weight[rA * DEG + hop];
    float wB = weight[rB * DEG + hop];
    if (mode == 0) {
        dst[rA * NCLASS + lane] = f2bf(accA);
        dst[rB * NCLASS + lane] = f2bf(accB);
    } else if (mode == 1) {
        dst[rA * NCLASS + lane] = f2bf(accA);
        dst[rB * NCLASS + lane] = f2bf(accB);
        float pA = bf2f(src[rA * NCLASS + lane]);   // prev hop output, coalesced
        float pB = bf2f(src[rB * NCLASS + lane]);
        float wpA = weight[rA * DEG + hop - 1];
        float wpB = weight[rB * DEG + hop - 1];
        out_acc[rA * NCLASS + lane] += wpA * pA + wA * accA;
        out_acc[rB * NCLASS + lane] += wpB * pB + wB * accB;
    } else {
        float vA = out_acc[rA * NCLASS + lane] + wA * accA;
        float mA = wave_max(vA);
        float eA2 = __expf(vA - mA);
        float sA2 = wave_sum(eA2);
        final_out[rA * NCLASS + lane] = vA - mA - __logf(sA2);

        float vB = out_acc[rB * NCLASS + lane] + wB * accB;
        float mB = wave_max(vB);
        float eB2 = __expf(vB - mB);
        float sB2 = wave_sum(eB2);
        final_out[rB * NCLASS + lane] = vB - mB - __logf(sB2);
    }
}

extern "C" void kernel_launch(void* const* d_in, const int* in_sizes, int n_in,
                              void* d_out, int out_size, void* d_ws, size_t ws_size,
                              hipStream_t stream) {
    const float* x    = (const float*)d_in[0];
    const int*   erow = (const int*)  d_in[1];
    const int*   ecol = (const int*)  d_in[2];
    const float* eval = (const float*)d_in[3];
    const float* W1   = (const float*)d_in[4];
    const float* b1   = (const float*)d_in[5];
    const float* W2   = (const float*)d_in[6];
    const float* b2   = (const float*)d_in[7];
    float* out = (float*)d_out;   // also the hop-accumulation buffer

    char* ws = (char*)d_ws;
    size_t off = 0;
    auto alloc = [&](size_t bytes) -> void* {
        void* p = ws + off;
        off = (off + bytes + 255) & ~(size_t)255;
        return p;
    };
    // Region A: staging (28.8 MB) is dead after phase2; xbf/cur0/cur1
    // (38.4 MB) reuse the same space. Stream ordering guarantees safety.
    char* regionA = (char*)alloc((size_t)N_NODES * NCLASS * 2 * 3);   // 38.4 MB
    int2* staging = (int2*)regionA;
    unsigned short* xbf  = (unsigned short*)regionA;
    unsigned short* cur0 = (unsigned short*)(regionA + (size_t)N_NODES * NCLASS * 2);
    unsigned short* cur1 = (unsigned short*)(regionA + (size_t)N_NODES * NCLASS * 4);

    int2*  edges_s     = (int2*)alloc((size_t)N_EDGES * 8);
    int*   row_ptr     = (int*) alloc((size_t)(N_NODES + 1) * 4);
    int*   fill        = (int*) alloc((size_t)NBUCK * 16 * 4);   // 64B-padded counters
    int*   bucket_base = (int*) alloc((size_t)NBUCK * 4);
    float* weight      = (float*)alloc((size_t)N_NODES * DEG * 4);

    const int EB = (N_EDGES + 255) / 256;            // 12500
    const int WB = ((N_NODES / 2) + 3) / 4;          // 12500 (4 row-pairs/block)
    const int GB = (N_NODES + GNODES - 1) / GNODES;  // 3125

    // CSR build: direct scatter -> bucket prefix -> compaction
    hipMemsetAsync(fill, 0, (size_t)NBUCK * 16 * 4, stream);
    phase1_bucket<<<EB, 256, 0, stream>>>(erow, ecol, eval, fill, staging);
    bucket_scan<<<1, 512, 0, stream>>>(fill, bucket_base, row_ptr);
    phase2_build<<<NBUCK, 256, 0, stream>>>(staging, fill, bucket_base, row_ptr, edges_s);

    // gating: weights + out = w0 * x, and bf16 copy of x (overwrites staging)
    gating_kernel<<<GB, 256, 0, stream>>>(x, W1, b1, W2, b2, weight, out, xbf);

    // 5 hops; hops 2/4 fold pairs of weighted terms into out, hop 5 finishes
    spmm_kernel<<<WB, 256, 0, stream>>>(xbf,  cur0, row_ptr, edges_s, weight, out, out, 1, 0);
    spmm_kernel<<<WB, 256, 0, stream>>>(cur0, cur1, row_ptr, edges_s, weight, out, out, 2, 1);
    spmm_kernel<<<WB, 256, 0, stream>>>(cur1, cur0, row_ptr, edges_s, weight, out, out, 3, 0);
    spmm_kernel<<<WB, 256, 0, stream>>>(cur0, cur1, row_ptr, edges_s, weight, out, out, 4, 1);
    spmm_kernel<<<WB, 256, 0, stream>>>(cur1, cur0, row_ptr, edges_s, weight, out, out, 5, 2);
}

// Round 9
// 682.427 us; speedup vs baseline: 10.5565x; 1.0581x over previous
//
#include <hip/hip_runtime.h>
#include <math.h>

#define N_NODES 100000
#define N_EDGES 3200000
#define NCLASS  64
#define TOPK    16
#define NHID    128
#define DEG     6

#define NBUCK   391          // ceil(100000/256) buckets of 256 rows
#define NSEG    8            // independent fill streams per bucket (blockIdx&7)
#define SEGCAP  1408         // per (bucket,segment); mean 1023

#define EB ((N_EDGES + 255) / 256)               // 12500 scatter blocks
#define GNODES 32                                 // nodes per gating block
#define GB ((N_NODES + GNODES - 1) / GNODES)      // 3125 gating blocks

// ---------- bf16 helpers ----------
__device__ __forceinline__ float bf2f(unsigned short u) {
    return __uint_as_float(((unsigned)u) << 16);
}
__device__ __forceinline__ unsigned short f2bf(float f) {
    unsigned u = __float_as_uint(f);
    u = (u + 0x7FFFu + ((u >> 16) & 1u)) >> 16;   // round-to-nearest-even
    return (unsigned short)u;
}

// ---------- wave helpers (wave64) ----------
__device__ __forceinline__ float wave_max(float v) {
    #pragma unroll
    for (int off = 1; off < 64; off <<= 1) v = fmaxf(v, __shfl_xor(v, off));
    return v;
}
__device__ __forceinline__ float wave_sum(float v) {
    #pragma unroll
    for (int off = 1; off < 64; off <<= 1) v += __shfl_xor(v, off);
    return v;
}

// ---------- fused: bucket scatter (blocks < EB) + gating (blocks >= EB) ----------
// Scatter is write-transaction-bound (1% VALU), gating is VALU/latency-bound
// (3% HBM): complementary pipes, so gating rides free under the scatter.
__global__ __launch_bounds__(256) void scatter_gating_kernel(
        const int* __restrict__ erow, const int* __restrict__ ecol,
        const float* __restrict__ eval, int* __restrict__ fill,
        int2* __restrict__ staging,
        const float* __restrict__ x,  const float* __restrict__ W1,
        const float* __restrict__ b1, const float* __restrict__ W2,
        const float* __restrict__ b2, float* __restrict__ weight,
        float* __restrict__ out_acc, unsigned short* __restrict__ xbf) {
    __shared__ float sW1t[TOPK * NHID];
    __shared__ float sb1[NHID];
    __shared__ float sW2[DEG * NHID];
    __shared__ float sb2[DEG];

    if (blockIdx.x < EB) {
        // ----- scatter path (r4 form: 8 sequential fill streams/bucket) -----
        int i = blockIdx.x * 256 + threadIdx.x;
        int s = blockIdx.x & 7;
        if (i < N_EDGES) {
            int   r = __builtin_nontemporal_load(&erow[i]);
            int   c = __builtin_nontemporal_load(&ecol[i]);
            float w = __builtin_nontemporal_load(&eval[i]);
            int b = r >> 8;
            int pos = atomicAdd(&fill[(s * NBUCK + b) * 16], 1);
            if (pos < SEGCAP) {
                int2 e;
                e.x = (c << 8) | (r & 255);   // col:17b << 8 | row_local:8b
                e.y = __float_as_int(w);
                staging[((size_t)b * NSEG + s) * SEGCAP + pos] = e;
            }
        }
        return;
    }

    // ----- gating path -----
    int tid = threadIdx.x;
    for (int idx = tid; idx < NHID * TOPK; idx += 256) {
        int k = idx / NHID, j = idx - k * NHID;
        sW1t[idx] = W1[j * TOPK + k];
    }
    for (int i = tid; i < NHID; i += 256) sb1[i] = b1[i];
    for (int i = tid; i < DEG * NHID; i += 256) sW2[i] = W2[i];
    if (tid < DEG) sb2[tid] = b2[tid];
    __syncthreads();

    int wave = tid >> 6;
    int lane = tid & 63;
    int gb = blockIdx.x - EB;

    for (int it = 0; it < GNODES / 4; it++) {
        int node = gb * GNODES + it * 4 + wave;
        if (node >= N_NODES) continue;

        float xv = x[node * NCLASS + lane];
        xbf[node * NCLASS + lane] = f2bf(xv);

        // full ascending bitonic sort of x across the wave (21 steps);
        // softmax monotonic -> top-16 of p == softmax of top-16 of x
        float v = xv;
        #pragma unroll
        for (int k = 2; k <= 64; k <<= 1) {
            #pragma unroll
            for (int j = k >> 1; j > 0; j >>= 1) {
                float o = __shfl_xor(v, j);
                bool keep_small = (((lane & j) == 0) == ((lane & k) == 0));
                v = keep_small ? fminf(v, o) : fmaxf(v, o);
            }
        }
        float m = __shfl(v, 63);
        float e = __expf(v - m);
        float s = wave_sum(e);
        float inv_s = 1.0f / s;

        float h0 = sb1[lane], h1 = sb1[lane + 64];
        #pragma unroll
        for (int k = 0; k < TOPK; k++) {
            float sv = __shfl(v, 63 - k);
            float tk = __expf(sv - m) * inv_s;
            h0 += tk * sW1t[k * NHID + lane];
            h1 += tk * sW1t[k * NHID + lane + 64];
        }
        h0 = (h0 > 0.f) ? h0 : 0.1f * h0;
        h1 = (h1 > 0.f) ? h1 : 0.1f * h1;

        float w[DEG];
        float wm = -1e30f;
        #pragma unroll
        for (int d = 0; d < DEG; d++) {
            float part = h0 * sW2[d * NHID + lane] + h1 * sW2[d * NHID + lane + 64];
            w[d] = wave_sum(part) + sb2[d];
            wm = fmaxf(wm, w[d]);
        }
        float wsum = 0.f;
        #pragma unroll
        for (int d = 0; d < DEG; d++) { w[d] = __expf(w[d] - wm); wsum += w[d]; }
        float inv = 1.0f / wsum;

        if (lane < DEG) weight[node * DEG + lane] = w[lane] * inv;
        out_acc[node * NCLASS + lane] = w[0] * inv * xv;
    }
}

// ---------- phase 2: per-bucket compaction + row_ptr (inline prefix base) ----------
__global__ __launch_bounds__(256) void phase2_build(
        const int2* __restrict__ staging, const int* __restrict__ fill,
        int* __restrict__ row_ptr, int2* __restrict__ edges_s) {
    __shared__ int lred[256];
    __shared__ int lhist[256];
    __shared__ int lscan[256];
    __shared__ int lfill[256];
    __shared__ int sseg[NSEG];
    int b = blockIdx.x, tid = threadIdx.x;

    // base_b = sum of totals of buckets < b (block reduction, no global scan)
    int part = 0;
    for (int j = tid; j < b; j += 256) {
        int t = 0;
        #pragma unroll
        for (int s = 0; s < NSEG; s++) t += min(fill[(s * NBUCK + j) * 16], SEGCAP);
        part += t;
    }
    lred[tid] = part;
    if (tid < NSEG) sseg[tid] = min(fill[(tid * NBUCK + b) * 16], SEGCAP);
    __syncthreads();
    for (int off = 128; off > 0; off >>= 1) {
        if (tid < off) lred[tid] += lred[tid + off];
        __syncthreads();
    }
    int base_b = lred[0];

    // own-bucket per-row histogram + scan
    lhist[tid] = 0;
    __syncthreads();
    for (int s = 0; s < NSEG; s++) {
        int c = sseg[s];
        const int2* seg = staging + ((size_t)b * NSEG + s) * SEGCAP;
        for (int j = tid; j < c; j += 256) atomicAdd(&lhist[seg[j].x & 255], 1);
    }
    __syncthreads();
    int v = lhist[tid];
    lscan[tid] = v;
    __syncthreads();
    for (int off = 1; off < 256; off <<= 1) {
        int t = (tid >= off) ? lscan[tid - off] : 0;
        __syncthreads();
        lscan[tid] += t;
        __syncthreads();
    }
    int excl = base_b + (lscan[tid] - v);
    int grow = b * 256 + tid;
    if (grow < N_NODES) row_ptr[grow] = excl;
    if (b == NBUCK - 1 && tid == 255) row_ptr[N_NODES] = excl + v;  // grand total
    lfill[tid] = excl;
    __syncthreads();
    for (int s = 0; s < NSEG; s++) {
        int c = sseg[s];
        const int2* seg = staging + ((size_t)b * NSEG + s) * SEGCAP;
        for (int j = tid; j < c; j += 256) {
            int2 e = seg[j];
            int rl = e.x & 255;
            int pos = atomicAdd(&lfill[rl], 1);
            edges_s[pos] = make_int2((int)(((unsigned)e.x) >> 8), e.y);
        }
    }
}

// ---------- SPMM gather groups (scalar SGPR edge stream) ----------
__device__ __forceinline__ void gather8(const unsigned short* __restrict__ src,
                                        const long long* __restrict__ edq,
                                        int e, int lane, float& acc) {
    long long q[8];
    #pragma unroll
    for (int k = 0; k < 8; k++) q[k] = __builtin_nontemporal_load(&edq[e + k]);
    float vk[8], fk[8];
    #pragma unroll
    for (int k = 0; k < 8; k++) {
        int col = __builtin_amdgcn_readfirstlane((int)(unsigned)q[k]);
        vk[k] = __int_as_float(__builtin_amdgcn_readfirstlane((int)(q[k] >> 32)));
        fk[k] = bf2f(src[col * NCLASS + lane]);
    }
    #pragma unroll
    for (int k = 0; k < 8; k++) acc += vk[k] * fk[k];
}

__device__ __forceinline__ void gather4(const unsigned short* __restrict__ src,
                                        const long long* __restrict__ edq,
                                        int e, int lane, float& acc) {
    long long q[4];
    #pragma unroll
    for (int k = 0; k < 4; k++) q[k] = __builtin_nontemporal_load(&edq[e + k]);
    float vk[4], fk[4];
    #pragma unroll
    for (int k = 0; k < 4; k++) {
        int col = __builtin_amdgcn_readfirstlane((int)(unsigned)q[k]);
        vk[k] = __int_as_float(__builtin_amdgcn_readfirstlane((int)(q[k] >> 32)));
        fk[k] = bf2f(src[col * NCLASS + lane]);
    }
    #pragma unroll
    for (int k = 0; k < 4; k++) acc += vk[k] * fk[k];
}

__device__ __forceinline__ float drain_row(const unsigned short* __restrict__ src,
                                           const long long* __restrict__ edq,
                                           int e, int end, int lane, float acc) {
    for (; e + 4 <= end; e += 4) gather4(src, edq, e, lane, acc);
    for (; e < end; e++) {
        long long q0 = __builtin_nontemporal_load(&edq[e]);
        int   c0 = __builtin_amdgcn_readfirstlane((int)(unsigned)q0);
        float v0 = __int_as_float(__builtin_amdgcn_readfirstlane((int)(q0 >> 32)));
        acc += v0 * bf2f(src[c0 * NCLASS + lane]);
    }
    return acc;
}

// ---------- SPMM hop: wave per ROW-PAIR, 16 gathers in flight ----------
// mode 0: write dst only.
// mode 1: write dst AND out_acc += w[hop-1]*src[node] + w[hop]*acc.
// mode 3: last hop — v = out_acc + w[hop-2]*prev2 + w[hop-1]*src + w[hop]*acc
//         -> log_softmax -> final_out.
__global__ __launch_bounds__(256) void spmm_kernel(
        const unsigned short* __restrict__ src, unsigned short* __restrict__ dst,
        const unsigned short* __restrict__ prev2,
        const int* __restrict__ row_ptr, const int2* __restrict__ edges_s,
        const float* __restrict__ weight,
        float* __restrict__ out_acc, float* __restrict__ final_out,
        int hop, int mode) {
    int wave = threadIdx.x >> 6;
    int lane = threadIdx.x & 63;
    int wid = blockIdx.x * 4 + wave;          // pair id
    int rA = wid * 2;
    if (rA >= N_NODES) return;
    int rB = rA + 1;                           // N_NODES even -> always valid

    int sA   = __builtin_amdgcn_readfirstlane(row_ptr[rA]);
    int endA = __builtin_amdgcn_readfirstlane(row_ptr[rA + 1]);
    int endB = __builtin_amdgcn_readfirstlane(row_ptr[rA + 2]);

    const long long* edq = (const long long*)edges_s;
    float accA = 0.f, accB = 0.f;
    int eA = sA, eB = endA;
    while (eA + 8 <= endA && eB + 8 <= endB) {
        gather8(src, edq, eA, lane, accA);
        gather8(src, edq, eB, lane, accB);
        eA += 8; eB += 8;
    }
    accA = drain_row(src, edq, eA, endA, lane, accA);
    accB = drain_row(src, edq, eB, endB, lane, accB);

    float wA = weight[rA * DEG + hop];
    float wB = weight[rB * DEG + hop];
    if (mode == 0) {
        dst[rA * NCLASS + lane] = f2bf(accA);
        dst[rB * NCLASS + lane] = f2bf(accB);
    } else if (mode == 1) {
        dst[rA * NCLASS + lane] = f2bf(accA);
        dst[rB * NCLASS + lane] = f2bf(accB);
        float pA = bf2f(src[rA * NCLASS + lane]);   // prev hop output, coalesced
        float pB = bf2f(src[rB * NCLASS + lane]);
        float wpA = weight[rA * DEG + hop - 1];
        float wpB = weight[rB * DEG + hop - 1];
        out_acc[rA * NCLASS + lane] += wpA * pA + wA * accA;
        out_acc[rB * NCLASS + lane] += wpB * pB + wB * accB;
    } else {
        float p1A = bf2f(src[rA * NCLASS + lane]);    // hop-1 output
        float p1B = bf2f(src[rB * NCLASS + lane]);
        float p2A = bf2f(prev2[rA * NCLASS + lane]);  // hop-2 output
        float p2B = bf2f(prev2[rB * NCLASS + lane]);
        float vA = out_acc[rA * NCLASS + lane]
                 + weight[rA * DEG + hop - 2] * p2A
                 + weight[rA * DEG + hop - 1] * p1A + wA * accA;
        float mA = wave_max(vA);
        float eA2 = __expf(vA - mA);
        float sA2 = wave_sum(eA2);
        final_out[rA * NCLASS + lane] = vA - mA - __logf(sA2);

        float vB = out_acc[rB * NCLASS + lane]
                 + weight[rB * DEG + hop - 2] * p2B
                 + weight[rB * DEG + hop - 1] * p1B + wB * accB;
        float mB = wave_max(vB);
        float eB2 = __expf(vB - mB);
        float sB2 = wave_sum(eB2);
        final_out[rB * NCLASS + lane] = vB - mB - __logf(sB2);
    }
}

extern "C" void kernel_launch(void* const* d_in, const int* in_sizes, int n_in,
                              void* d_out, int out_size, void* d_ws, size_t ws_size,
                              hipStream_t stream) {
    const float* x    = (const float*)d_in[0];
    const int*   erow = (const int*)  d_in[1];
    const int*   ecol = (const int*)  d_in[2];
    const float* eval = (const float*)d_in[3];
    const float* W1   = (const float*)d_in[4];
    const float* b1   = (const float*)d_in[5];
    const float* W2   = (const float*)d_in[6];
    const float* b2   = (const float*)d_in[7];
    float* out = (float*)d_out;   // also the hop-accumulation buffer

    char* ws = (char*)d_ws;
    size_t off = 0;
    auto alloc = [&](size_t bytes) -> void* {
        void* p = ws + off;
        off = (off + bytes + 255) & ~(size_t)255;
        return p;
    };
    // staging (35.2 MB) is dead after phase2; cur0/cur1 (25.6 MB) reuse it.
    // xbf is SEPARATE: gating writes it concurrently with the scatter.
    char* regionS = (char*)alloc((size_t)NBUCK * NSEG * SEGCAP * 8);   // 35.2 MB
    int2* staging = (int2*)regionS;
    unsigned short* cur0 = (unsigned short*)regionS;
    unsigned short* cur1 = (unsigned short*)(regionS + (size_t)N_NODES * NCLASS * 2);
    unsigned short* xbf  = (unsigned short*)alloc((size_t)N_NODES * NCLASS * 2);

    int2*  edges_s = (int2*)alloc((size_t)N_EDGES * 8);
    int*   row_ptr = (int*) alloc((size_t)(N_NODES + 1) * 4);
    int*   fill    = (int*) alloc((size_t)NSEG * NBUCK * 16 * 4);   // 64B-padded
    float* weight  = (float*)alloc((size_t)N_NODES * DEG * 4);

    const int WB = ((N_NODES / 2) + 3) / 4;          // 12500 (4 row-pairs/block)

    hipMemsetAsync(fill, 0, (size_t)NSEG * NBUCK * 16 * 4, stream);
    // fused: scatter (12500 blocks) + gating (3125 blocks) in one dispatch
    scatter_gating_kernel<<<EB + GB, 256, 0, stream>>>(
        erow, ecol, eval, fill, staging, x, W1, b1, W2, b2, weight, out, xbf);
    phase2_build<<<NBUCK, 256, 0, stream>>>(staging, fill, row_ptr, edges_s);

    // 5 hops; h2 folds (w1,w2), h5 folds (w3,w4,w5) + log_softmax
    spmm_kernel<<<WB, 256, 0, stream>>>(xbf,  cur0, cur0, row_ptr, edges_s, weight, out, out, 1, 0);
    spmm_kernel<<<WB, 256, 0, stream>>>(cur0, cur1, cur0, row_ptr, edges_s, weight, out, out, 2, 1);
    spmm_kernel<<<WB, 256, 0, stream>>>(cur1, cur0, cur0, row_ptr, edges_s, weight, out, out, 3, 0);
    spmm_kernel<<<WB, 256, 0, stream>>>(cur0, cur1, cur0, row_ptr, edges_s, weight, out, out, 4, 0);
    spmm_kernel<<<WB, 256, 0, stream>>>(cur1, cur0, cur0, row_ptr, edges_s, weight, out, out, 5, 3);
}

// Round 10
// 670.869 us; speedup vs baseline: 10.7383x; 1.0172x over previous
//
#include <hip/hip_runtime.h>
#include <math.h>

#define N_NODES 100000
#define N_EDGES 3200000
#define NCLASS  64
#define TOPK    16
#define NHID    128
#define DEG     6

#define NBUCK   391          // ceil(100000/256) buckets of 256 rows
#define NSEG    8            // independent fill streams per bucket
#define SEGCAP  1408         // per (bucket,segment); mean 1023

#define EB ((N_EDGES + 255) / 256)               // 12500 scatter blocks
#define GNODES 32                                 // nodes per gating block
#define GB ((N_NODES + GNODES - 1) / GNODES)      // 3125 gating blocks

// ---------- bf16 helpers ----------
__device__ __forceinline__ float bf2f(unsigned short u) {
    return __uint_as_float(((unsigned)u) << 16);
}
__device__ __forceinline__ unsigned short f2bf(float f) {
    unsigned u = __float_as_uint(f);
    u = (u + 0x7FFFu + ((u >> 16) & 1u)) >> 16;   // round-to-nearest-even
    return (unsigned short)u;
}

// ---------- wave helpers (wave64) ----------
__device__ __forceinline__ float wave_max(float v) {
    #pragma unroll
    for (int off = 1; off < 64; off <<= 1) v = fmaxf(v, __shfl_xor(v, off));
    return v;
}
__device__ __forceinline__ float wave_sum(float v) {
    #pragma unroll
    for (int off = 1; off < 64; off <<= 1) v += __shfl_xor(v, off);
    return v;
}

// ---------- fused scatter + gating, INTERLEAVED (idx%5==0 -> gating) ----------
// Scatter is write-transaction-bound (1% VALU), gating is VALU/latency-bound
// (3% HBM). Interleaving keeps both populations co-resident on every CU for
// the whole dispatch (r9's head/tail split ran them serially).
__global__ __launch_bounds__(256) void scatter_gating_kernel(
        const int* __restrict__ erow, const int* __restrict__ ecol,
        const float* __restrict__ eval, int* __restrict__ fill,
        int2* __restrict__ staging,
        const float* __restrict__ x,  const float* __restrict__ W1,
        const float* __restrict__ b1, const float* __restrict__ W2,
        const float* __restrict__ b2, float* __restrict__ weight,
        float* __restrict__ out_acc, unsigned short* __restrict__ xbf) {
    __shared__ float sW1t[TOPK * NHID];
    __shared__ float sb1[NHID];
    __shared__ float sW2[DEG * NHID];
    __shared__ float sb2[DEG];

    unsigned bi = blockIdx.x;
    if (bi % 5 != 0) {
        // ----- scatter path: scatter_id = bi - bi/5 - 1 -----
        int sid = (int)(bi - bi / 5u - 1u);
        int i = sid * 256 + threadIdx.x;
        int s = sid & 7;
        if (i < N_EDGES) {
            int   r = __builtin_nontemporal_load(&erow[i]);
            int   c = __builtin_nontemporal_load(&ecol[i]);
            float w = __builtin_nontemporal_load(&eval[i]);
            int b = r >> 8;
            int pos = atomicAdd(&fill[(s * NBUCK + b) * 16], 1);
            if (pos < SEGCAP) {
                int2 e;
                e.x = (c << 8) | (r & 255);   // col:17b << 8 | row_local:8b
                e.y = __float_as_int(w);
                staging[((size_t)b * NSEG + s) * SEGCAP + pos] = e;
            }
        }
        return;
    }

    // ----- gating path: gating_id = bi/5 -----
    int gb = (int)(bi / 5u);
    int tid = threadIdx.x;
    for (int idx = tid; idx < NHID * TOPK; idx += 256) {
        int k = idx / NHID, j = idx - k * NHID;
        sW1t[idx] = W1[j * TOPK + k];
    }
    for (int i = tid; i < NHID; i += 256) sb1[i] = b1[i];
    for (int i = tid; i < DEG * NHID; i += 256) sW2[i] = W2[i];
    if (tid < DEG) sb2[tid] = b2[tid];
    __syncthreads();

    int wave = tid >> 6;
    int lane = tid & 63;

    for (int it = 0; it < GNODES / 4; it++) {
        int node = gb * GNODES + it * 4 + wave;
        if (node >= N_NODES) continue;

        float xv = x[node * NCLASS + lane];
        xbf[node * NCLASS + lane] = f2bf(xv);

        // full ascending bitonic sort of x across the wave (21 steps);
        // softmax monotonic -> top-16 of p == softmax of top-16 of x
        float v = xv;
        #pragma unroll
        for (int k = 2; k <= 64; k <<= 1) {
            #pragma unroll
            for (int j = k >> 1; j > 0; j >>= 1) {
                float o = __shfl_xor(v, j);
                bool keep_small = (((lane & j) == 0) == ((lane & k) == 0));
                v = keep_small ? fminf(v, o) : fmaxf(v, o);
            }
        }
        float m = __shfl(v, 63);
        float e = __expf(v - m);
        float s = wave_sum(e);
        float inv_s = 1.0f / s;

        float h0 = sb1[lane], h1 = sb1[lane + 64];
        #pragma unroll
        for (int k = 0; k < TOPK; k++) {
            float sv = __shfl(v, 63 - k);
            float tk = __expf(sv - m) * inv_s;
            h0 += tk * sW1t[k * NHID + lane];
            h1 += tk * sW1t[k * NHID + lane + 64];
        }
        h0 = (h0 > 0.f) ? h0 : 0.1f * h0;
        h1 = (h1 > 0.f) ? h1 : 0.1f * h1;

        float w[DEG];
        float wm = -1e30f;
        #pragma unroll
        for (int d = 0; d < DEG; d++) {
            float part = h0 * sW2[d * NHID + lane] + h1 * sW2[d * NHID + lane + 64];
            w[d] = wave_sum(part) + sb2[d];
            wm = fmaxf(wm, w[d]);
        }
        float wsum = 0.f;
        #pragma unroll
        for (int d = 0; d < DEG; d++) { w[d] = __expf(w[d] - wm); wsum += w[d]; }
        float inv = 1.0f / wsum;

        if (lane < DEG) weight[node * DEG + lane] = w[lane] * inv;
        out_acc[node * NCLASS + lane] = w[0] * inv * xv;
    }
}

// ---------- phase 2: per-bucket compaction + row_ptr (inline prefix base) ----------
__global__ __launch_bounds__(256) void phase2_build(
        const int2* __restrict__ staging, const int* __restrict__ fill,
        int* __restrict__ row_ptr, int2* __restrict__ edges_s) {
    __shared__ int lred[256];
    __shared__ int lhist[256];
    __shared__ int lscan[256];
    __shared__ int lfill[256];
    __shared__ int sseg[NSEG];
    int b = blockIdx.x, tid = threadIdx.x;

    int part = 0;
    for (int j = tid; j < b; j += 256) {
        int t = 0;
        #pragma unroll
        for (int s = 0; s < NSEG; s++) t += min(fill[(s * NBUCK + j) * 16], SEGCAP);
        part += t;
    }
    lred[tid] = part;
    if (tid < NSEG) sseg[tid] = min(fill[(tid * NBUCK + b) * 16], SEGCAP);
    __syncthreads();
    for (int off = 128; off > 0; off >>= 1) {
        if (tid < off) lred[tid] += lred[tid + off];
        __syncthreads();
    }
    int base_b = lred[0];

    lhist[tid] = 0;
    __syncthreads();
    for (int s = 0; s < NSEG; s++) {
        int c = sseg[s];
        const int2* seg = staging + ((size_t)b * NSEG + s) * SEGCAP;
        for (int j = tid; j < c; j += 256) atomicAdd(&lhist[seg[j].x & 255], 1);
    }
    __syncthreads();
    int v = lhist[tid];
    lscan[tid] = v;
    __syncthreads();
    for (int off = 1; off < 256; off <<= 1) {
        int t = (tid >= off) ? lscan[tid - off] : 0;
        __syncthreads();
        lscan[tid] += t;
        __syncthreads();
    }
    int excl = base_b + (lscan[tid] - v);
    int grow = b * 256 + tid;
    if (grow < N_NODES) row_ptr[grow] = excl;
    if (b == NBUCK - 1 && tid == 255) row_ptr[N_NODES] = excl + v;
    lfill[tid] = excl;
    __syncthreads();
    for (int s = 0; s < NSEG; s++) {
        int c = sseg[s];
        const int2* seg = staging + ((size_t)b * NSEG + s) * SEGCAP;
        for (int j = tid; j < c; j += 256) {
            int2 e = seg[j];
            int rl = e.x & 255;
            int pos = atomicAdd(&lfill[rl], 1);
            edges_s[pos] = make_int2((int)(((unsigned)e.x) >> 8), e.y);
        }
    }
}

// ---------- SPMM gather groups (scalar SGPR edge stream) ----------
__device__ __forceinline__ void gather8(const unsigned short* __restrict__ src,
                                        const long long* __restrict__ edq,
                                        int e, int lane, float& acc) {
    long long q[8];
    #pragma unroll
    for (int k = 0; k < 8; k++) q[k] = __builtin_nontemporal_load(&edq[e + k]);
    float vk[8], fk[8];
    #pragma unroll
    for (int k = 0; k < 8; k++) {
        int col = __builtin_amdgcn_readfirstlane((int)(unsigned)q[k]);
        vk[k] = __int_as_float(__builtin_amdgcn_readfirstlane((int)(q[k] >> 32)));
        fk[k] = bf2f(src[col * NCLASS + lane]);
    }
    #pragma unroll
    for (int k = 0; k < 8; k++) acc += vk[k] * fk[k];
}

__device__ __forceinline__ void gather4(const unsigned short* __restrict__ src,
                                        const long long* __restrict__ edq,
                                        int e, int lane, float& acc) {
    long long q[4];
    #pragma unroll
    for (int k = 0; k < 4; k++) q[k] = __builtin_nontemporal_load(&edq[e + k]);
    float vk[4], fk[4];
    #pragma unroll
    for (int k = 0; k < 4; k++) {
        int col = __builtin_amdgcn_readfirstlane((int)(unsigned)q[k]);
        vk[k] = __int_as_float(__builtin_amdgcn_readfirstlane((int)(q[k] >> 32)));
        fk[k] = bf2f(src[col * NCLASS + lane]);
    }
    #pragma unroll
    for (int k = 0; k < 4; k++) acc += vk[k] * fk[k];
}

__device__ __forceinline__ float drain_row(const unsigned short* __restrict__ src,
                                           const long long* __restrict__ edq,
                                           int e, int end, int lane, float acc) {
    for (; e + 4 <= end; e += 4) gather4(src, edq, e, lane, acc);
    for (; e < end; e++) {
        long long q0 = __builtin_nontemporal_load(&edq[e]);
        int   c0 = __builtin_amdgcn_readfirstlane((int)(unsigned)q0);
        float v0 = __int_as_float(__builtin_amdgcn_readfirstlane((int)(q0 >> 32)));
        acc += v0 * bf2f(src[c0 * NCLASS + lane]);
    }
    return acc;
}

// ---------- SPMM hop: wave per 4 ROWS, 4 chains x gather8 = 32 in flight ----------
// mode 0: write dst only.
// mode 1: write dst AND out_acc += w[hop-1]*src[node] + w[hop]*acc.
// mode 3: last hop — v = out_acc + w[hop-2]*prev2 + w[hop-1]*src + w[hop]*acc
//         -> log_softmax -> final_out.
__global__ __launch_bounds__(256) void spmm_kernel(
        const unsigned short* __restrict__ src, unsigned short* __restrict__ dst,
        const unsigned short* __restrict__ prev2,
        const int* __restrict__ row_ptr, const int2* __restrict__ edges_s,
        const float* __restrict__ weight,
        float* __restrict__ out_acc, float* __restrict__ final_out,
        int hop, int mode) {
    int wave = threadIdx.x >> 6;
    int lane = threadIdx.x & 63;
    int wid = blockIdx.x * 4 + wave;          // 0..24999
    int r0 = wid * 4;
    if (r0 >= N_NODES) return;                 // exact fit: 25000*4 = 100000

    int p0 = __builtin_amdgcn_readfirstlane(row_ptr[r0]);
    int p1 = __builtin_amdgcn_readfirstlane(row_ptr[r0 + 1]);
    int p2 = __builtin_amdgcn_readfirstlane(row_ptr[r0 + 2]);
    int p3 = __builtin_amdgcn_readfirstlane(row_ptr[r0 + 3]);
    int p4 = __builtin_amdgcn_readfirstlane(row_ptr[r0 + 4]);

    const long long* edq = (const long long*)edges_s;
    float acc[4] = {0.f, 0.f, 0.f, 0.f};
    int e0 = p0, e1 = p1, e2 = p2, e3 = p3;
    // 4 independent chains, 32 gathers in flight
    while (e0 + 8 <= p1 && e1 + 8 <= p2 && e2 + 8 <= p3 && e3 + 8 <= p4) {
        gather8(src, edq, e0, lane, acc[0]);
        gather8(src, edq, e1, lane, acc[1]);
        gather8(src, edq, e2, lane, acc[2]);
        gather8(src, edq, e3, lane, acc[3]);
        e0 += 8; e1 += 8; e2 += 8; e3 += 8;
    }
    acc[0] = drain_row(src, edq, e0, p1, lane, acc[0]);
    acc[1] = drain_row(src, edq, e1, p2, lane, acc[1]);
    acc[2] = drain_row(src, edq, e2, p3, lane, acc[2]);
    acc[3] = drain_row(src, edq, e3, p4, lane, acc[3]);

    #pragma unroll
    for (int k = 0; k < 4; k++) {
        int r = r0 + k;
        float a = acc[k];
        float w = weight[r * DEG + hop];
        if (mode == 0) {
            dst[r * NCLASS + lane] = f2bf(a);
        } else if (mode == 1) {
            dst[r * NCLASS + lane] = f2bf(a);
            float p  = bf2f(src[r * NCLASS + lane]);   // prev hop out, coalesced
            float wp = weight[r * DEG + hop - 1];
            out_acc[r * NCLASS + lane] += wp * p + w * a;
        } else {
            float q1 = bf2f(src[r * NCLASS + lane]);    // hop-1 output
            float q2 = bf2f(prev2[r * NCLASS + lane]);  // hop-2 output
            float v = out_acc[r * NCLASS + lane]
                    + weight[r * DEG + hop - 2] * q2
                    + weight[r * DEG + hop - 1] * q1 + w * a;
            float m = wave_max(v);
            float ee = __expf(v - m);
            float ss = wave_sum(ee);
            final_out[r * NCLASS + lane] = v - m - __logf(ss);
        }
    }
}

extern "C" void kernel_launch(void* const* d_in, const int* in_sizes, int n_in,
                              void* d_out, int out_size, void* d_ws, size_t ws_size,
                              hipStream_t stream) {
    const float* x    = (const float*)d_in[0];
    const int*   erow = (const int*)  d_in[1];
    const int*   ecol = (const int*)  d_in[2];
    const float* eval = (const float*)d_in[3];
    const float* W1   = (const float*)d_in[4];
    const float* b1   = (const float*)d_in[5];
    const float* W2   = (const float*)d_in[6];
    const float* b2   = (const float*)d_in[7];
    float* out = (float*)d_out;   // also the hop-accumulation buffer

    char* ws = (char*)d_ws;
    size_t off = 0;
    auto alloc = [&](size_t bytes) -> void* {
        void* p = ws + off;
        off = (off + bytes + 255) & ~(size_t)255;
        return p;
    };
    // staging (35.2 MB) is dead after phase2; cur0/cur1 (25.6 MB) reuse it.
    // xbf is SEPARATE: gating writes it concurrently with the scatter.
    char* regionS = (char*)alloc((size_t)NBUCK * NSEG * SEGCAP * 8);   // 35.2 MB
    int2* staging = (int2*)regionS;
    unsigned short* cur0 = (unsigned short*)regionS;
    unsigned short* cur1 = (unsigned short*)(regionS + (size_t)N_NODES * NCLASS * 2);
    unsigned short* xbf  = (unsigned short*)alloc((size_t)N_NODES * NCLASS * 2);

    int2*  edges_s = (int2*)alloc((size_t)N_EDGES * 8);
    int*   row_ptr = (int*) alloc((size_t)(N_NODES + 1) * 4);
    int*   fill    = (int*) alloc((size_t)NSEG * NBUCK * 16 * 4);   // 64B-padded
    float* weight  = (float*)alloc((size_t)N_NODES * DEG * 4);

    const int WB = (N_NODES / 4 + 3) / 4;            // 6250 (4 waves x 4 rows)

    hipMemsetAsync(fill, 0, (size_t)NSEG * NBUCK * 16 * 4, stream);
    // fused: scatter (12500) + gating (3125) interleaved every 5th block
    scatter_gating_kernel<<<EB + GB, 256, 0, stream>>>(
        erow, ecol, eval, fill, staging, x, W1, b1, W2, b2, weight, out, xbf);
    phase2_build<<<NBUCK, 256, 0, stream>>>(staging, fill, row_ptr, edges_s);

    // 5 hops; h2 folds (w1,w2), h5 folds (w3,w4,w5) + log_softmax
    spmm_kernel<<<WB, 256, 0, stream>>>(xbf,  cur0, cur0, row_ptr, edges_s, weight, out, out, 1, 0);
    spmm_kernel<<<WB, 256, 0, stream>>>(cur0, cur1, cur0, row_ptr, edges_s, weight, out, out, 2, 1);
    spmm_kernel<<<WB, 256, 0, stream>>>(cur1, cur0, cur0, row_ptr, edges_s, weight, out, out, 3, 0);
    spmm_kernel<<<WB, 256, 0, stream>>>(cur0, cur1, cur0, row_ptr, edges_s, weight, out, out, 4, 0);
    spmm_kernel<<<WB, 256, 0, stream>>>(cur1, cur0, cur0, row_ptr, edges_s, weight, out, out, 5, 3);
}